// Round 1
// baseline (206.111 us; speedup 1.0000x reference)
//
#include <hip/hip_runtime.h>

// Problem constants (fixed by the reference):
//   TOTAL_NODES = 262144, NUM_GRAPHS = 1024, MAX_NODES = 512, D = 256
#define NUM_GRAPHS 1024
#define MAX_NODES  512
#define DIM        256
#define D4         (DIM / 4)   // 64 float4 per row

// ---------------------------------------------------------------------------
// Kernel 1: per-graph start offsets + counts via binary search on the sorted
// batch_idx. Handles both int64 and int32 underlying storage: if int64
// (little-endian, values < 2^31), the int32 view at index n-1 is a hi-word
// and equals 0; if int32, it's the largest graph id (nonzero for this data).
// ---------------------------------------------------------------------------
__global__ void compute_offsets_kernel(const int* __restrict__ bidx32, int n,
                                       int* __restrict__ starts,
                                       int* __restrict__ counts) {
    int g = blockIdx.x * blockDim.x + threadIdx.x;
    if (g >= NUM_GRAPHS) return;
    const bool is64 = (bidx32[n - 1] == 0);

    // lower_bound(g)
    int lo = 0, hi = n;
    while (lo < hi) {
        int mid = (lo + hi) >> 1;
        int v = is64 ? bidx32[2 * mid] : bidx32[mid];
        if (v < g) lo = mid + 1; else hi = mid;
    }
    int s = lo;

    // lower_bound(g + 1)
    int g1 = g + 1;
    lo = 0; hi = n;
    while (lo < hi) {
        int mid = (lo + hi) >> 1;
        int v = is64 ? bidx32[2 * mid] : bidx32[mid];
        if (v < g1) lo = mid + 1; else hi = mid;
    }

    starts[g] = s;
    counts[g] = lo - s;
}

// ---------------------------------------------------------------------------
// Kernel 2: write enc_states. One float4 per loop-step per thread; output is
// written exactly once per element (occupied slots copy the node row,
// padding slots write zeros). Reads and writes are both fully coalesced.
// ---------------------------------------------------------------------------
__global__ void scatter_states_kernel(const float4* __restrict__ emb,
                                      const int* __restrict__ starts,
                                      const int* __restrict__ counts,
                                      float4* __restrict__ out) {
    const int total = NUM_GRAPHS * MAX_NODES * D4;   // 33,554,432
    const int stride = gridDim.x * blockDim.x;
    for (int v = blockIdx.x * blockDim.x + threadIdx.x; v < total; v += stride) {
        int row  = v >> 6;              // / D4
        int lane = v & (D4 - 1);
        int g    = row >> 9;            // / MAX_NODES
        int slot = row & (MAX_NODES - 1);
        float4 val = make_float4(0.f, 0.f, 0.f, 0.f);
        if (slot < counts[g]) {
            val = emb[(size_t)(starts[g] + slot) * D4 + lane];
        }
        out[v] = val;
    }
}

// ---------------------------------------------------------------------------
// Kernel 3: enc_mask — first counts[g] slots of each row are 1.
// Written as float32 (the harness reads the concatenated output as f32).
// ---------------------------------------------------------------------------
__global__ void mask_kernel(const int* __restrict__ counts,
                            float* __restrict__ mask) {
    int idx = blockIdx.x * blockDim.x + threadIdx.x;
    if (idx >= NUM_GRAPHS * MAX_NODES) return;
    int g    = idx >> 9;                // / MAX_NODES
    int slot = idx & (MAX_NODES - 1);
    mask[idx] = (slot < counts[g]) ? 1.0f : 0.0f;
}

extern "C" void kernel_launch(void* const* d_in, const int* in_sizes, int n_in,
                              void* d_out, int out_size, void* d_ws, size_t ws_size,
                              hipStream_t stream) {
    const float* node_emb = (const float*)d_in[0];
    const int*   bidx32   = (const int*)d_in[1];   // int32 view; kernel detects int64
    const int    n        = in_sizes[1];           // 262144

    int* starts = (int*)d_ws;
    int* counts = starts + NUM_GRAPHS;

    // 1. offsets + counts (tiny)
    compute_offsets_kernel<<<(NUM_GRAPHS + 255) / 256, 256, 0, stream>>>(
        bidx32, n, starts, counts);

    // 2. enc_states: 33.5M float4, grid-stride over 2048 blocks x 256 threads
    scatter_states_kernel<<<2048, 256, 0, stream>>>(
        (const float4*)node_emb, starts, counts, (float4*)d_out);

    // 3. enc_mask appended after enc_states
    float* mask = (float*)d_out + (size_t)NUM_GRAPHS * MAX_NODES * DIM;
    mask_kernel<<<(NUM_GRAPHS * MAX_NODES) / 256, 256, 0, stream>>>(counts, mask);
}

// Round 3
// 188.326 us; speedup vs baseline: 1.0944x; 1.0944x over previous
//
#include <hip/hip_runtime.h>

// Problem constants (fixed by the reference):
//   TOTAL_NODES = 262144, NUM_GRAPHS = 1024, MAX_NODES = 512, D = 256
#define NUM_GRAPHS 1024
#define MAX_NODES  512
#define DIM        256
#define D4         (DIM / 4)          // 64 float4 per row
#define TOTAL_V4   (NUM_GRAPHS * MAX_NODES * D4)   // 33,554,432 float4
#define NTHREADS   (2048 * 256)       // 524,288 = TOTAL_V4 / 64

// Native clang vector type: __builtin_nontemporal_* requires a pointer to
// integer/float/vector-of-such, which HIP's float4 struct is NOT.
typedef float f4 __attribute__((ext_vector_type(4)));

// ---------------------------------------------------------------------------
// Kernel 1: boundary scan. batch_idx is sorted, so starts[g] = lower_bound(g)
// can be found by comparing adjacent elements: where bidx[i-1] < bidx[i],
// every g in (bidx[i-1], bidx[i]] starts at i. O(n) coalesced reads, no
// dependent-load chains. starts has NUM_GRAPHS+1 entries (sentinel
// starts[1024] = n) so counts[g] = starts[g+1] - starts[g].
// Handles int64 vs int32 storage: for little-endian int64 (values < 2^31)
// the int32 view at odd index n-1 is a hi-word == 0; for int32 it's the max
// graph id (nonzero for this data).
// ---------------------------------------------------------------------------
__global__ void scan_offsets_kernel(const int* __restrict__ bidx32, int n,
                                    int* __restrict__ starts) {
    int i = blockIdx.x * blockDim.x + threadIdx.x;
    if (i >= n) return;
    const bool is64 = (bidx32[n - 1] == 0);
    const int cur  = is64 ? bidx32[2 * i] : bidx32[i];
    const int prev = (i == 0) ? -1 : (is64 ? bidx32[2 * (i - 1)] : bidx32[i - 1]);
    for (int g = prev + 1; g <= cur; ++g) starts[g] = i;   // usually 0 iters
    if (i == n - 1) {
        for (int g = cur + 1; g <= NUM_GRAPHS; ++g) starts[g] = n;
    }
}

// ---------------------------------------------------------------------------
// Kernel 2: write enc_states (every element exactly once: copy or zero) and
// enc_mask, fused. Exact-sized grid: 524,288 threads x 64 iterations.
// Per-thread invariants across iterations (stride 524,288 float4 => row
// advances by 8192 => slot and lane are fixed, g advances by 16):
//   lane = tid & 63, slot = (tid>>6) & 511, g = (tid>>15) + 16*it
// Streams (emb in, out) use nontemporal hints; starts stays cached.
// ---------------------------------------------------------------------------
__global__ void __launch_bounds__(256)
scatter_states_kernel(const f4* __restrict__ emb,
                      const int* __restrict__ starts,
                      f4* __restrict__ out,
                      float* __restrict__ mask) {
    const int tid  = blockIdx.x * blockDim.x + threadIdx.x;   // 0..524287
    const int lane = tid & (D4 - 1);
    const int row0 = tid >> 6;
    const int slot = row0 & (MAX_NODES - 1);
    const int g0   = row0 >> 9;                               // 0..15

#pragma unroll 8
    for (int it = 0; it < 64; ++it) {
        const int g = g0 + it * 16;
        const int s = starts[g];
        const int c = starts[g + 1] - s;
        f4 val = (f4)(0.f);
        if (slot < c) {
            val = __builtin_nontemporal_load(&emb[(size_t)(s + slot) * D4 + lane]);
        }
        __builtin_nontemporal_store(val, &out[tid + (size_t)it * NTHREADS]);
    }

    // enc_mask: exactly one element per thread (524,288 total), as f32 0/1.
    const int mg = tid >> 9;
    const int ms = tid & (MAX_NODES - 1);
    const int mc = starts[mg + 1] - starts[mg];
    __builtin_nontemporal_store((ms < mc) ? 1.0f : 0.0f, &mask[tid]);
}

extern "C" void kernel_launch(void* const* d_in, const int* in_sizes, int n_in,
                              void* d_out, int out_size, void* d_ws, size_t ws_size,
                              hipStream_t stream) {
    const float* node_emb = (const float*)d_in[0];
    const int*   bidx32   = (const int*)d_in[1];   // int32 view; kernels detect int64
    const int    n        = in_sizes[1];           // 262144

    int* starts = (int*)d_ws;                      // NUM_GRAPHS + 1 ints

    scan_offsets_kernel<<<(n + 255) / 256, 256, 0, stream>>>(bidx32, n, starts);

    float* mask = (float*)d_out + (size_t)NUM_GRAPHS * MAX_NODES * DIM;
    scatter_states_kernel<<<NTHREADS / 256, 256, 0, stream>>>(
        (const f4*)node_emb, starts, (f4*)d_out, mask);
}